// Round 9
// baseline (248.042 us; speedup 1.0000x reference)
//
#include <hip/hip_runtime.h>

#define B_ 8
#define N_ 2048
#define D_ 1024

using u16 = unsigned short;
typedef __attribute__((ext_vector_type(8))) short short8;
typedef __attribute__((ext_vector_type(16))) float f32x16;
typedef __attribute__((ext_vector_type(4))) float float4v;
typedef __attribute__((ext_vector_type(4))) int int4v;

static __device__ __forceinline__ u16 f2bf(float f) {
  unsigned u = __float_as_uint(f);
  u += 0x7FFFu + ((u >> 16) & 1u);   // round-to-nearest-even
  return (u16)(u >> 16);
}

static __device__ __forceinline__ void gload16(const void* g, void* l) {
  __builtin_amdgcn_global_load_lds((const __attribute__((address_space(1))) void*)g,
                                   (__attribute__((address_space(3))) void*)l, 16, 0, 0);
}

// stage one 64-row slab (64 rows x 64 cols bf16); linear LDS dest, global col
// pre-swizzled (rule 21: swizzle both sides or neither).
static __device__ __forceinline__ void stage_slab(u16* __restrict__ L,
                                                  const u16* __restrict__ g,
                                                  int slab, int kof, int w) {
  gload16(g + (size_t)(slab * 64) * 1024 + kof, L + slab * 4096 + w * 512);
}

#define MF32(a, b, c) __builtin_amdgcn_mfma_f32_32x32x16_bf16(a, b, c, 0, 0, 0)

// =====================================================================
// 4-phase 256x256 bf16 GEMM (C = A * B^T), K = 1024 (16 K-tiles of 64),
// mfma_f32_32x32x16. 512 threads = 8 waves (2M x 4N); per-wave out 128x64.
// VERIFIED R7 BODY. Staging-safety invariant: a slab region is DMA'd only
// after a barrier that follows the last lgkmcnt-complete reads of it
// (P3's t+2 A0,A2 stage is 2 barriers after P1's last A0/A2 reads).
// Entry wait: vmcnt(2) counted (never drains in main loop).
// =====================================================================

template<int S1, int S2, int VM>
__device__ __forceinline__ void tile_body(u16* __restrict__ cur, u16* __restrict__ nxt,
                                          const u16* __restrict__ gA, const u16* __restrict__ gB,
                                          int kn1, int kn2,
                                          int w, int wr, int wc, int l,
                                          f32x16 (&acc)[4][2])
{
  const int l31 = l & 31, lhi = l >> 5, l7 = l & 7;
  const u16* Ap = cur + (wr * 128) * 64;
  const u16* Bp = cur + 16384 + (wc * 64) * 64;

#define AFR(rt, ks) (*(const short8*)(Ap + ((rt) * 32 + l31) * 64 + ((((ks) * 2 + lhi) ^ l7) * 8)))
#define BFR(ct, ks) (*(const short8*)(Bp + ((ct) * 32 + l31) * 64 + ((((ks) * 2 + lhi) ^ l7) * 8)))

  short8 a2[2][2];     // transient A frags
  short8 b[2][4];      // B[ct][ks], live across phases

  if constexpr (VM == 2) asm volatile("s_waitcnt vmcnt(2)" ::: "memory");
  else                   asm volatile("s_waitcnt vmcnt(0)" ::: "memory");
  __builtin_amdgcn_s_barrier();

  // ---- P0: rt0,1 x ct0,1 x ks0,1 ----
  #pragma unroll
  for (int r = 0; r < 2; ++r) { a2[r][0] = AFR(r, 0); a2[r][1] = AFR(r, 1); }
  #pragma unroll
  for (int cc = 0; cc < 2; ++cc) { b[cc][0] = BFR(cc, 0); b[cc][1] = BFR(cc, 1); }
  if constexpr (S1) { stage_slab(nxt, gA, 1, kn1, w); stage_slab(nxt, gA, 3, kn1, w); }
  __builtin_amdgcn_s_barrier();
  __builtin_amdgcn_s_setprio(1);
  #pragma unroll
  for (int r = 0; r < 2; ++r)
    #pragma unroll
    for (int cc = 0; cc < 2; ++cc)
      #pragma unroll
      for (int ks = 0; ks < 2; ++ks)
        acc[r][cc] = MF32(a2[r][ks], b[cc][ks], acc[r][cc]);
  __builtin_amdgcn_s_setprio(0);
  __builtin_amdgcn_s_barrier();

  // ---- P1: rt0,1 x ks2,3 ----
  #pragma unroll
  for (int r = 0; r < 2; ++r) { a2[r][0] = AFR(r, 2); a2[r][1] = AFR(r, 3); }
  #pragma unroll
  for (int cc = 0; cc < 2; ++cc) { b[cc][2] = BFR(cc, 2); b[cc][3] = BFR(cc, 3); }
  if constexpr (S1) { stage_slab(nxt + 16384, gB, 0, kn1, w); stage_slab(nxt + 16384, gB, 1, kn1, w); }
  __builtin_amdgcn_s_barrier();
  __builtin_amdgcn_s_setprio(1);
  #pragma unroll
  for (int r = 0; r < 2; ++r)
    #pragma unroll
    for (int cc = 0; cc < 2; ++cc)
      #pragma unroll
      for (int ks = 0; ks < 2; ++ks)
        acc[r][cc] = MF32(a2[r][ks], b[cc][2 + ks], acc[r][cc]);
  __builtin_amdgcn_s_setprio(0);
  __builtin_amdgcn_s_barrier();

  // ---- P2: rt2,3 x ks0,1 (reuse b[..][0,1]) ----
  #pragma unroll
  for (int r = 0; r < 2; ++r) { a2[r][0] = AFR(r + 2, 0); a2[r][1] = AFR(r + 2, 1); }
  if constexpr (S1) { stage_slab(nxt + 16384, gB, 2, kn1, w); stage_slab(nxt + 16384, gB, 3, kn1, w); }
  __builtin_amdgcn_s_barrier();
  __builtin_amdgcn_s_setprio(1);
  #pragma unroll
  for (int r = 0; r < 2; ++r)
    #pragma unroll
    for (int cc = 0; cc < 2; ++cc)
      #pragma unroll
      for (int ks = 0; ks < 2; ++ks)
        acc[r + 2][cc] = MF32(a2[r][ks], b[cc][ks], acc[r + 2][cc]);
  __builtin_amdgcn_s_setprio(0);
  __builtin_amdgcn_s_barrier();

  // ---- P3: rt2,3 x ks2,3; early-stage t+2 A0,A2 into cur ----
  #pragma unroll
  for (int r = 0; r < 2; ++r) { a2[r][0] = AFR(r + 2, 2); a2[r][1] = AFR(r + 2, 3); }
  if constexpr (S2) { stage_slab(cur, gA, 0, kn2, w); stage_slab(cur, gA, 2, kn2, w); }
  __builtin_amdgcn_s_barrier();
  __builtin_amdgcn_s_setprio(1);
  #pragma unroll
  for (int r = 0; r < 2; ++r)
    #pragma unroll
    for (int cc = 0; cc < 2; ++cc)
      #pragma unroll
      for (int ks = 0; ks < 2; ++ks)
        acc[r + 2][cc] = MF32(a2[r][ks], b[cc][2 + ks], acc[r + 2][cc]);
  __builtin_amdgcn_s_setprio(0);
  __builtin_amdgcn_s_barrier();
#undef AFR
#undef BFR
}

// MODE 0: C0 = bf16 out [M x 1024] with +bias  (GEMM1; grid 256, 1 tile/block)
// MODE 1: batched, dual f32 out: attn = raw, out = dinv_i*attn*dinv_j
//         (GEMM2; grid 256, 2 adjacent col-tiles per block, A-panel reused)
template<int MODE>
__global__ __launch_bounds__(512, 2)
void gemm8p(const u16* __restrict__ Abase, const u16* __restrict__ Bbase,
            const float* __restrict__ aux,   // bias (MODE0) or dinv (MODE1)
            void* __restrict__ C0, float* __restrict__ C1)
{
  __shared__ u16 lds[2][32768];
  const int tid = threadIdx.x;
  const int w = tid >> 6, l = tid & 63;

  int tm0, tnbase, z = 0;
  const int bid = blockIdx.x;                   // 256 blocks both modes
  const int s = (bid & 7) * 32 + (bid >> 3);    // XCD-contiguous
  if (MODE == 0) {
    tm0 = (s >> 2) << 8;
    tnbase = (s & 3) << 8;
  } else {
    z = s >> 5;                                 // each XCD owns one batch
    const int r = s & 31;
    tm0 = (r >> 2) << 8;
    tnbase = (r & 3) << 9;                      // 2 tiles of 256 wide
  }
  const u16* A  = Abase + (MODE ? (size_t)z * N_ * D_ : 0);
  const u16* Bm = (MODE ? A : Bbase);

  // staging source (pre-swizzled global col -> linear LDS dest = swizzled layout)
  const int sc = ((l & 7) ^ (l >> 3)) * 8;               // element col (swizzled)
  const int sr = w * 8 + (l >> 3);                       // row within 64-row slab
  const u16* gA = A + (size_t)(tm0 + sr) * 1024 + sc;

  const int wr = w >> 2, wc = w & 3;
  const int l31 = l & 31, lhi = l >> 5;
  const int NJT = MODE ? 2 : 1;

  #pragma unroll 1
  for (int jt = 0; jt < NJT; ++jt) {
    const int tn0 = tnbase + (MODE ? (jt << 8) : 0);
    const u16* gB = Bm + (size_t)(tn0 + sr) * 1024 + sc;

    f32x16 acc[4][2];
    #pragma unroll
    for (int m = 0; m < 4; ++m)
      #pragma unroll
      for (int n = 0; n < 2; ++n)
        acc[m][n] = (f32x16)(0.f);

    u16* cur = &lds[0][0];
    u16* nxt = &lds[1][0];

    // prologue: tile0 all 8 slabs; tile1 A0,A2
    #pragma unroll
    for (int s4 = 0; s4 < 4; ++s4) stage_slab(cur, gA, s4, 0, w);
    #pragma unroll
    for (int s4 = 0; s4 < 4; ++s4) stage_slab(cur + 16384, gB, s4, 0, w);
    stage_slab(nxt, gA, 0, 64, w);
    stage_slab(nxt, gA, 2, 64, w);

    for (int t = 0; t < 14; ++t) {
      tile_body<1, 1, 2>(cur, nxt, gA, gB, (t + 1) * 64, (t + 2) * 64,
                         w, wr, wc, l, acc);
      u16* tmp = cur; cur = nxt; nxt = tmp;
    }
    tile_body<1, 0, 2>(cur, nxt, gA, gB, 15 * 64, 0, w, wr, wc, l, acc);
    { u16* tmp = cur; cur = nxt; nxt = tmp; }
    tile_body<0, 0, 0>(cur, nxt, gA, gB, 0, 0, w, wr, wc, l, acc);
    asm volatile("s_waitcnt vmcnt(0)" ::: "memory");     // drain DMA

    // ---- epilogue: 32x32 C/D layout col=l&31, row=(reg&3)+8*(reg>>2)+4*(l>>5)
    const int rbase = tm0 + wr * 128 + lhi * 4;
    const int cb    = tn0 + wc * 64 + l31;

    if (MODE == 0) {
      u16* C = (u16*)C0;
      const float bv0 = aux[cb], bv1 = aux[cb + 32];
      #pragma unroll
      for (int rt = 0; rt < 4; ++rt)
        #pragma unroll
        for (int g = 0; g < 4; ++g)
          #pragma unroll
          for (int jj = 0; jj < 4; ++jj) {
            const int row = rbase + rt * 32 + g * 8 + jj;
            C[(size_t)row * 1024 + cb]      = f2bf(acc[rt][0][g * 4 + jj] + bv0);
            C[(size_t)row * 1024 + cb + 32] = f2bf(acc[rt][1][g * 4 + jj] + bv1);
          }
    } else {
      float* Cattn = (float*)C0 + (size_t)z * N_ * N_;
      float* Cout  = C1 + (size_t)z * N_ * N_;
      const float* dv = aux + z * N_;
      const float dj0 = dv[cb], dj1 = dv[cb + 32];
      #pragma unroll
      for (int rt = 0; rt < 4; ++rt)
        #pragma unroll
        for (int g = 0; g < 4; ++g)
          #pragma unroll
          for (int jj = 0; jj < 4; ++jj) {
            const int row = rbase + rt * 32 + g * 8 + jj;
            const float di = dv[row];
            const float a0 = acc[rt][0][g * 4 + jj];
            const float a1 = acc[rt][1][g * 4 + jj];
            const size_t off = (size_t)row * N_ + cb;
            __builtin_nontemporal_store(a0,            Cattn + off);
            __builtin_nontemporal_store(a0 * di * dj0, Cout + off);
            __builtin_nontemporal_store(a1,            Cattn + off + 32);
            __builtin_nontemporal_store(a1 * di * dj1, Cout + off + 32);
          }
    }
  }
}

// ---------------- fused q f32->bf16 cvt + column sums + W1 cvt ----------------
__global__ void cvt_fused(const float* __restrict__ q, u16* __restrict__ qbf,
                          float* __restrict__ qsum,
                          const float* __restrict__ W1, u16* __restrict__ w1bf) {
  if (blockIdx.x < 512) {
    const int wi = blockIdx.x * 256 + threadIdx.x;
    const int d0 = (wi & 127) * 8;
    const int rc = (wi >> 7) & 127;
    const int b  = wi >> 14;
    const size_t base = ((size_t)b * N_ + rc * 16) * D_ + d0;
    float s[8];
    #pragma unroll
    for (int k = 0; k < 8; ++k) s[k] = 0.f;
    #pragma unroll 4
    for (int r = 0; r < 16; ++r) {
      const float4v* p = (const float4v*)(q + base + (size_t)r * D_);
      float4v x = p[0], y = p[1];
      union { u16 h[8]; int4v v; } o;
      o.h[0] = f2bf(x.x); o.h[1] = f2bf(x.y); o.h[2] = f2bf(x.z); o.h[3] = f2bf(x.w);
      o.h[4] = f2bf(y.x); o.h[5] = f2bf(y.y); o.h[6] = f2bf(y.z); o.h[7] = f2bf(y.w);
      *(int4v*)(qbf + base + (size_t)r * D_) = o.v;
      s[0] += x.x; s[1] += x.y; s[2] += x.z; s[3] += x.w;
      s[4] += y.x; s[5] += y.y; s[6] += y.z; s[7] += y.w;
    }
    float* qs = qsum + b * D_ + d0;
    #pragma unroll
    for (int k = 0; k < 8; ++k) atomicAdd(qs + k, s[k]);
  } else {
    const int i = (blockIdx.x - 512) * 256 + threadIdx.x;
    const float4v* p = (const float4v*)W1 + (size_t)i * 2;
    float4v a = p[0], b = p[1];
    union { u16 h[8]; int4v v; } r;
    r.h[0] = f2bf(a.x); r.h[1] = f2bf(a.y); r.h[2] = f2bf(a.z); r.h[3] = f2bf(a.w);
    r.h[4] = f2bf(b.x); r.h[5] = f2bf(b.y); r.h[6] = f2bf(b.z); r.h[7] = f2bf(b.w);
    ((int4v*)w1bf)[i] = r.v;
  }
}

// ---------------- exact f32 rowsum stats (split-K, atomics) -------------------
// s[b,e] = sum_d qsum[b,d] * W1[e,d] + N*b1[e]   (grid (32, 16))
__global__ void s_kernel(const float* __restrict__ qsum, const float* __restrict__ W1,
                         const float* __restrict__ b1, float* __restrict__ s) {
  const int idx = blockIdx.x * 256 + threadIdx.x;   // b*D + e
  const int b = idx >> 10, e = idx & (D_ - 1);
  const int d0 = blockIdx.y * 64;
  const float4v* wp = (const float4v*)(W1 + (size_t)e * D_ + d0);
  const float4v* qp = (const float4v*)(qsum + b * D_ + d0);
  float acc = 0.f;
  #pragma unroll 4
  for (int t = 0; t < 16; ++t) {
    float4v wv = wp[t], qv = qp[t];
    acc += wv.x * qv.x + wv.y * qv.y + wv.z * qv.z + wv.w * qv.w;
  }
  if (blockIdx.y == 0) acc += (float)N_ * b1[e];
  atomicAdd(&s[b * D_ + e], acc);
}

// t[b,d] = sum_e W1[e,d] * s[b,e]  (grid (32,17): y<16 -> t; y==16,x<8 -> c)
__global__ void tc_kernel(const float* __restrict__ W1, const float* __restrict__ s,
                          const float* __restrict__ b1,
                          float* __restrict__ tv, float* __restrict__ c) {
  if (blockIdx.y < 16) {
    const int idx = blockIdx.x * 256 + threadIdx.x;   // b*D + d
    const int b = idx >> 10, d = idx & (D_ - 1);
    const int e0 = blockIdx.y * 64;
    const float* wp = W1 + (size_t)e0 * D_ + d;
    const float* sp = s + b * D_ + e0;
    float acc = 0.f;
    #pragma unroll 8
    for (int e = 0; e < 64; ++e) acc += wp[(size_t)e * D_] * sp[e];
    atomicAdd(&tv[b * D_ + d], acc);
  } else if (blockIdx.x < 8) {
    const int b = blockIdx.x;
    const int tid = threadIdx.x;
    float acc = 0.f;
    #pragma unroll
    for (int t = 0; t < 4; ++t) {
      const int e = tid + t * 256;
      acc += b1[e] * s[b * D_ + e];
    }
    __shared__ float red[4];
    #pragma unroll
    for (int off = 32; off; off >>= 1) acc += __shfl_down(acc, off);
    if ((tid & 63) == 0) red[tid >> 6] = acc;
    __syncthreads();
    if (tid == 0) c[b] = red[0] + red[1] + red[2] + red[3];
  }
}

// dinv[b,i] = rsqrt(max(q[b,i,:] . t[b,:] + c[b], 1))
__global__ void rowdinv_kernel(const float* __restrict__ q, const float* __restrict__ tv,
                               const float* __restrict__ c, float* __restrict__ dinv) {
  const int row  = blockIdx.x * 4 + (threadIdx.x >> 6);   // [0, B*N)
  const int lane = threadIdx.x & 63;
  const int b    = row >> 11;
  const float4v* p  = (const float4v*)(q + (size_t)row * D_);
  const float4v* tp = (const float4v*)(tv + b * D_);
  float acc = 0.f;
  #pragma unroll
  for (int it = 0; it < 4; ++it) {
    float4v qv = p[it * 64 + lane];
    float4v tw = tp[it * 64 + lane];
    acc += qv.x * tw.x + qv.y * tw.y + qv.z * tw.z + qv.w * tw.w;
  }
  #pragma unroll
  for (int off = 32; off; off >>= 1) acc += __shfl_down(acc, off);
  if (lane == 0) dinv[row] = rsqrtf(fmaxf(acc + c[b], 1.0f));
}

extern "C" void kernel_launch(void* const* d_in, const int* in_sizes, int n_in,
                              void* d_out, int out_size, void* d_ws, size_t ws_size,
                              hipStream_t stream) {
  const float* q  = (const float*)d_in[0];
  // d_in[1] = k (unused), d_in[2] = v (unused)
  const float* W1 = (const float*)d_in[3];
  const float* b1 = (const float*)d_in[4];

  float* out  = (float*)d_out;                      // [B,N,N] normalized
  float* attn = out + (size_t)B_ * N_ * N_;         // [B,N,N] raw attn

  char* ws = (char*)d_ws;
  u16*   qbf  = (u16*)ws;                                   // 32 MiB
  u16*   qout = (u16*)(ws + (size_t)33554432);              // 32 MiB
  u16*   w1bf = (u16*)(ws + (size_t)67108864);              // 2 MiB
  float* qsum = (float*)(ws + (size_t)69206016);            // 32 KiB
  float* s    = (float*)(ws + (size_t)69238784);            // 32 KiB
  float* tv   = (float*)(ws + (size_t)69271552);            // 32 KiB
  float* c    = (float*)(ws + (size_t)69304320);            // 256 B
  float* dinv = (float*)(ws + (size_t)69304576);            // 64 KiB

  // zero the accumulated stats (qsum, s, tv, c) in one memset
  hipMemsetAsync(qsum, 0, 3 * B_ * D_ * sizeof(float) + 256, stream);

  // 1. convert q (+column sums) and W1 to bf16 (fused)
  cvt_fused<<<1024, 256, 0, stream>>>(q, qbf, qsum, W1, w1bf);

  // 2. GEMM1 (4-phase 256^2, mfma 32x32x16): qout = qbf @ w1bf^T + b1 (bf16)
  gemm8p<0><<<256, 512, 0, stream>>>(qbf, w1bf, b1, qout, nullptr);

  // 3. exact f32 rowsum stats: s -> (t, c) -> dinv
  s_kernel<<<dim3(B_ * D_ / 256, 16), 256, 0, stream>>>(qsum, W1, b1, s);
  tc_kernel<<<dim3(B_ * D_ / 256, 17), 256, 0, stream>>>(W1, s, b1, tv, c);
  rowdinv_kernel<<<(B_ * N_) / 4, 256, 0, stream>>>(q, tv, c, dinv);

  // 4. GEMM2 (4-phase 256^2, batched, 2 col-tiles/block) + fused normalization
  gemm8p<1><<<256, 512, 0, stream>>>(qout, nullptr, dinv, attn, out);
}

// Round 10
// 227.313 us; speedup vs baseline: 1.0912x; 1.0912x over previous
//
#include <hip/hip_runtime.h>

#define B_ 8
#define N_ 2048
#define D_ 1024

using u16 = unsigned short;
typedef __attribute__((ext_vector_type(8))) short short8;
typedef __attribute__((ext_vector_type(16))) float f32x16;
typedef __attribute__((ext_vector_type(4))) float float4v;
typedef __attribute__((ext_vector_type(4))) int int4v;

static __device__ __forceinline__ u16 f2bf(float f) {
  unsigned u = __float_as_uint(f);
  u += 0x7FFFu + ((u >> 16) & 1u);   // round-to-nearest-even
  return (u16)(u >> 16);
}

static __device__ __forceinline__ void gload16(const void* g, void* l) {
  __builtin_amdgcn_global_load_lds((const __attribute__((address_space(1))) void*)g,
                                   (__attribute__((address_space(3))) void*)l, 16, 0, 0);
}

// stage one 64-row slab (64 rows x 64 cols bf16); linear LDS dest, global col
// pre-swizzled (rule 21: swizzle both sides or neither).
static __device__ __forceinline__ void stage_slab(u16* __restrict__ L,
                                                  const u16* __restrict__ g,
                                                  int slab, int kof, int w) {
  gload16(g + (size_t)(slab * 64) * 1024 + kof, L + slab * 4096 + w * 512);
}

#define MF32(a, b, c) __builtin_amdgcn_mfma_f32_32x32x16_bf16(a, b, c, 0, 0, 0)

// =====================================================================
// 4-phase 256x256 bf16 GEMM (C = A * B^T), K = 1024 (16 K-tiles of 64),
// mfma_f32_32x32x16. 512 threads = 8 waves (2M x 4N); per-wave out 128x64.
// VERIFIED R7 BODY (217.7 us). Staging-safety invariant: a slab region is
// DMA'd only after a barrier that follows the last lgkmcnt-complete reads
// of it (P3's t+2 A0,A2 stage is 2 barriers after P1's last A0/A2 reads).
// Entry wait: vmcnt(2) counted (never drains in main loop).
// =====================================================================

template<int S1, int S2, int VM>
__device__ __forceinline__ void tile_body(u16* __restrict__ cur, u16* __restrict__ nxt,
                                          const u16* __restrict__ gA, const u16* __restrict__ gB,
                                          int kn1, int kn2,
                                          int w, int wr, int wc, int l,
                                          f32x16 (&acc)[4][2])
{
  const int l31 = l & 31, lhi = l >> 5, l7 = l & 7;
  const u16* Ap = cur + (wr * 128) * 64;
  const u16* Bp = cur + 16384 + (wc * 64) * 64;

#define AFR(rt, ks) (*(const short8*)(Ap + ((rt) * 32 + l31) * 64 + ((((ks) * 2 + lhi) ^ l7) * 8)))
#define BFR(ct, ks) (*(const short8*)(Bp + ((ct) * 32 + l31) * 64 + ((((ks) * 2 + lhi) ^ l7) * 8)))

  short8 a2[2][2];     // transient A frags
  short8 b[2][4];      // B[ct][ks], live across phases

  if constexpr (VM == 2) asm volatile("s_waitcnt vmcnt(2)" ::: "memory");
  else                   asm volatile("s_waitcnt vmcnt(0)" ::: "memory");
  __builtin_amdgcn_s_barrier();

  // ---- P0: rt0,1 x ct0,1 x ks0,1 ----
  #pragma unroll
  for (int r = 0; r < 2; ++r) { a2[r][0] = AFR(r, 0); a2[r][1] = AFR(r, 1); }
  #pragma unroll
  for (int cc = 0; cc < 2; ++cc) { b[cc][0] = BFR(cc, 0); b[cc][1] = BFR(cc, 1); }
  if constexpr (S1) { stage_slab(nxt, gA, 1, kn1, w); stage_slab(nxt, gA, 3, kn1, w); }
  __builtin_amdgcn_s_barrier();
  __builtin_amdgcn_s_setprio(1);
  #pragma unroll
  for (int r = 0; r < 2; ++r)
    #pragma unroll
    for (int cc = 0; cc < 2; ++cc)
      #pragma unroll
      for (int ks = 0; ks < 2; ++ks)
        acc[r][cc] = MF32(a2[r][ks], b[cc][ks], acc[r][cc]);
  __builtin_amdgcn_s_setprio(0);
  __builtin_amdgcn_s_barrier();

  // ---- P1: rt0,1 x ks2,3 ----
  #pragma unroll
  for (int r = 0; r < 2; ++r) { a2[r][0] = AFR(r, 2); a2[r][1] = AFR(r, 3); }
  #pragma unroll
  for (int cc = 0; cc < 2; ++cc) { b[cc][2] = BFR(cc, 2); b[cc][3] = BFR(cc, 3); }
  if constexpr (S1) { stage_slab(nxt + 16384, gB, 0, kn1, w); stage_slab(nxt + 16384, gB, 1, kn1, w); }
  __builtin_amdgcn_s_barrier();
  __builtin_amdgcn_s_setprio(1);
  #pragma unroll
  for (int r = 0; r < 2; ++r)
    #pragma unroll
    for (int cc = 0; cc < 2; ++cc)
      #pragma unroll
      for (int ks = 0; ks < 2; ++ks)
        acc[r][cc] = MF32(a2[r][ks], b[cc][2 + ks], acc[r][cc]);
  __builtin_amdgcn_s_setprio(0);
  __builtin_amdgcn_s_barrier();

  // ---- P2: rt2,3 x ks0,1 (reuse b[..][0,1]) ----
  #pragma unroll
  for (int r = 0; r < 2; ++r) { a2[r][0] = AFR(r + 2, 0); a2[r][1] = AFR(r + 2, 1); }
  if constexpr (S1) { stage_slab(nxt + 16384, gB, 2, kn1, w); stage_slab(nxt + 16384, gB, 3, kn1, w); }
  __builtin_amdgcn_s_barrier();
  __builtin_amdgcn_s_setprio(1);
  #pragma unroll
  for (int r = 0; r < 2; ++r)
    #pragma unroll
    for (int cc = 0; cc < 2; ++cc)
      #pragma unroll
      for (int ks = 0; ks < 2; ++ks)
        acc[r + 2][cc] = MF32(a2[r][ks], b[cc][ks], acc[r + 2][cc]);
  __builtin_amdgcn_s_setprio(0);
  __builtin_amdgcn_s_barrier();

  // ---- P3: rt2,3 x ks2,3; early-stage t+2 A0,A2 into cur ----
  #pragma unroll
  for (int r = 0; r < 2; ++r) { a2[r][0] = AFR(r + 2, 2); a2[r][1] = AFR(r + 2, 3); }
  if constexpr (S2) { stage_slab(cur, gA, 0, kn2, w); stage_slab(cur, gA, 2, kn2, w); }
  __builtin_amdgcn_s_barrier();
  __builtin_amdgcn_s_setprio(1);
  #pragma unroll
  for (int r = 0; r < 2; ++r)
    #pragma unroll
    for (int cc = 0; cc < 2; ++cc)
      #pragma unroll
      for (int ks = 0; ks < 2; ++ks)
        acc[r + 2][cc] = MF32(a2[r][ks], b[cc][2 + ks], acc[r + 2][cc]);
  __builtin_amdgcn_s_setprio(0);
  __builtin_amdgcn_s_barrier();
#undef AFR
#undef BFR
}

// MODE 0: C0 = bf16 out [M x 1024] with +bias  (GEMM1; grid 256)
// MODE 1: batched, dual f32 out: attn = raw, out = dinv_i*attn*dinv_j (grid 512)
template<int MODE>
__global__ __launch_bounds__(512, 2)
void gemm8p(const u16* __restrict__ Abase, const u16* __restrict__ Bbase,
            const float* __restrict__ aux,   // bias (MODE0) or dinv (MODE1)
            void* __restrict__ C0, float* __restrict__ C1)
{
  __shared__ u16 lds[2][32768];
  const int tid = threadIdx.x;
  const int w = tid >> 6, l = tid & 63;

  int tm0, tn0, z = 0;
  if (MODE == 0) {
    const int bid = blockIdx.x;                 // 256 blocks
    const int s = (bid & 7) * 32 + (bid >> 3);  // XCD-contiguous
    tm0 = (s >> 2) << 8;
    tn0 = (s & 3) << 8;
  } else {
    const int bid = blockIdx.x;                 // 512 blocks
    const int s = (bid & 7) * 64 + (bid >> 3);  // each XCD owns one batch
    z  = s >> 6;
    tm0 = ((s >> 3) & 7) << 8;
    tn0 = (s & 7) << 8;
  }
  const u16* A  = Abase + (MODE ? (size_t)z * N_ * D_ : 0);
  const u16* Bm = (MODE ? A : Bbase);

  // staging source (pre-swizzled global col -> linear LDS dest = swizzled layout)
  const int sc = ((l & 7) ^ (l >> 3)) * 8;               // element col (swizzled)
  const int sr = w * 8 + (l >> 3);                       // row within 64-row slab
  const u16* gA = A  + (size_t)(tm0 + sr) * 1024 + sc;
  const u16* gB = Bm + (size_t)(tn0 + sr) * 1024 + sc;

  const int wr = w >> 2, wc = w & 3;

  f32x16 acc[4][2];
  #pragma unroll
  for (int m = 0; m < 4; ++m)
    #pragma unroll
    for (int n = 0; n < 2; ++n)
      acc[m][n] = (f32x16)(0.f);

  u16* cur = &lds[0][0];
  u16* nxt = &lds[1][0];

  // prologue: tile0 all 8 slabs; tile1 A0,A2
  #pragma unroll
  for (int s4 = 0; s4 < 4; ++s4) stage_slab(cur, gA, s4, 0, w);
  #pragma unroll
  for (int s4 = 0; s4 < 4; ++s4) stage_slab(cur + 16384, gB, s4, 0, w);
  stage_slab(nxt, gA, 0, 64, w);
  stage_slab(nxt, gA, 2, 64, w);

  for (int t = 0; t < 14; ++t) {
    tile_body<1, 1, 2>(cur, nxt, gA, gB, (t + 1) * 64, (t + 2) * 64,
                       w, wr, wc, l, acc);
    u16* tmp = cur; cur = nxt; nxt = tmp;
  }
  tile_body<1, 0, 2>(cur, nxt, gA, gB, 15 * 64, 0, w, wr, wc, l, acc);
  { u16* tmp = cur; cur = nxt; nxt = tmp; }
  tile_body<0, 0, 0>(cur, nxt, gA, gB, 0, 0, w, wr, wc, l, acc);
  asm volatile("s_waitcnt vmcnt(0)" ::: "memory");       // drain DMA

  // ---- epilogue: 32x32 C/D layout col=l&31, row=(reg&3)+8*(reg>>2)+4*(l>>5) --
  const int l31 = l & 31, lhi = l >> 5;
  const int rbase = tm0 + wr * 128 + lhi * 4;
  const int cb    = tn0 + wc * 64 + l31;

  if (MODE == 0) {
    u16* C = (u16*)C0;
    const float bv0 = aux[cb], bv1 = aux[cb + 32];
    #pragma unroll
    for (int rt = 0; rt < 4; ++rt)
      #pragma unroll
      for (int g = 0; g < 4; ++g)
        #pragma unroll
        for (int jj = 0; jj < 4; ++jj) {
          const int row = rbase + rt * 32 + g * 8 + jj;
          C[(size_t)row * 1024 + cb]      = f2bf(acc[rt][0][g * 4 + jj] + bv0);
          C[(size_t)row * 1024 + cb + 32] = f2bf(acc[rt][1][g * 4 + jj] + bv1);
        }
  } else {
    float* Cattn = (float*)C0 + (size_t)z * N_ * N_;
    float* Cout  = C1 + (size_t)z * N_ * N_;
    const float* dv = aux + z * N_;
    const float dj0 = dv[cb], dj1 = dv[cb + 32];
    #pragma unroll
    for (int rt = 0; rt < 4; ++rt)
      #pragma unroll
      for (int g = 0; g < 4; ++g)
        #pragma unroll
        for (int jj = 0; jj < 4; ++jj) {
          const int row = rbase + rt * 32 + g * 8 + jj;
          const float di = dv[row];
          const float a0 = acc[rt][0][g * 4 + jj];
          const float a1 = acc[rt][1][g * 4 + jj];
          const size_t off = (size_t)row * N_ + cb;
          Cattn[off]      = a0;
          Cout[off]       = a0 * di * dj0;
          Cattn[off + 32] = a1;
          Cout[off + 32]  = a1 * di * dj1;
        }
  }
}

// ---------------- fused q f32->bf16 cvt + column sums + W1 cvt ----------------
__global__ void cvt_fused(const float* __restrict__ q, u16* __restrict__ qbf,
                          float* __restrict__ qsum,
                          const float* __restrict__ W1, u16* __restrict__ w1bf) {
  if (blockIdx.x < 512) {
    const int wi = blockIdx.x * 256 + threadIdx.x;
    const int d0 = (wi & 127) * 8;
    const int rc = (wi >> 7) & 127;
    const int b  = wi >> 14;
    const size_t base = ((size_t)b * N_ + rc * 16) * D_ + d0;
    float s[8];
    #pragma unroll
    for (int k = 0; k < 8; ++k) s[k] = 0.f;
    #pragma unroll 4
    for (int r = 0; r < 16; ++r) {
      const float4v* p = (const float4v*)(q + base + (size_t)r * D_);
      float4v x = p[0], y = p[1];
      union { u16 h[8]; int4v v; } o;
      o.h[0] = f2bf(x.x); o.h[1] = f2bf(x.y); o.h[2] = f2bf(x.z); o.h[3] = f2bf(x.w);
      o.h[4] = f2bf(y.x); o.h[5] = f2bf(y.y); o.h[6] = f2bf(y.z); o.h[7] = f2bf(y.w);
      *(int4v*)(qbf + base + (size_t)r * D_) = o.v;
      s[0] += x.x; s[1] += x.y; s[2] += x.z; s[3] += x.w;
      s[4] += y.x; s[5] += y.y; s[6] += y.z; s[7] += y.w;
    }
    float* qs = qsum + b * D_ + d0;
    #pragma unroll
    for (int k = 0; k < 8; ++k) atomicAdd(qs + k, s[k]);
  } else {
    const int i = (blockIdx.x - 512) * 256 + threadIdx.x;
    const float4v* p = (const float4v*)W1 + (size_t)i * 2;
    float4v a = p[0], b = p[1];
    union { u16 h[8]; int4v v; } r;
    r.h[0] = f2bf(a.x); r.h[1] = f2bf(a.y); r.h[2] = f2bf(a.z); r.h[3] = f2bf(a.w);
    r.h[4] = f2bf(b.x); r.h[5] = f2bf(b.y); r.h[6] = f2bf(b.z); r.h[7] = f2bf(b.w);
    ((int4v*)w1bf)[i] = r.v;
  }
}

// ---------------- exact f32 rowsum stats (split-K, atomics) -------------------
// s[b,e] = sum_d qsum[b,d] * W1[e,d] + N*b1[e]   (grid (32, 16))
__global__ void s_kernel(const float* __restrict__ qsum, const float* __restrict__ W1,
                         const float* __restrict__ b1, float* __restrict__ s) {
  const int idx = blockIdx.x * 256 + threadIdx.x;   // b*D + e
  const int b = idx >> 10, e = idx & (D_ - 1);
  const int d0 = blockIdx.y * 64;
  const float4v* wp = (const float4v*)(W1 + (size_t)e * D_ + d0);
  const float4v* qp = (const float4v*)(qsum + b * D_ + d0);
  float acc = 0.f;
  #pragma unroll 4
  for (int t = 0; t < 16; ++t) {
    float4v wv = wp[t], qv = qp[t];
    acc += wv.x * qv.x + wv.y * qv.y + wv.z * qv.z + wv.w * qv.w;
  }
  if (blockIdx.y == 0) acc += (float)N_ * b1[e];
  atomicAdd(&s[b * D_ + e], acc);
}

// t[b,d] = sum_e W1[e,d] * s[b,e]  (grid (32,17): y<16 -> t; y==16,x<8 -> c)
__global__ void tc_kernel(const float* __restrict__ W1, const float* __restrict__ s,
                          const float* __restrict__ b1,
                          float* __restrict__ tv, float* __restrict__ c) {
  if (blockIdx.y < 16) {
    const int idx = blockIdx.x * 256 + threadIdx.x;   // b*D + d
    const int b = idx >> 10, d = idx & (D_ - 1);
    const int e0 = blockIdx.y * 64;
    const float* wp = W1 + (size_t)e0 * D_ + d;
    const float* sp = s + b * D_ + e0;
    float acc = 0.f;
    #pragma unroll 8
    for (int e = 0; e < 64; ++e) acc += wp[(size_t)e * D_] * sp[e];
    atomicAdd(&tv[b * D_ + d], acc);
  } else if (blockIdx.x < 8) {
    const int b = blockIdx.x;
    const int tid = threadIdx.x;
    float acc = 0.f;
    #pragma unroll
    for (int t = 0; t < 4; ++t) {
      const int e = tid + t * 256;
      acc += b1[e] * s[b * D_ + e];
    }
    __shared__ float red[4];
    #pragma unroll
    for (int off = 32; off; off >>= 1) acc += __shfl_down(acc, off);
    if ((tid & 63) == 0) red[tid >> 6] = acc;
    __syncthreads();
    if (tid == 0) c[b] = red[0] + red[1] + red[2] + red[3];
  }
}

// dinv[b,i] = rsqrt(max(q[b,i,:] . t[b,:] + c[b], 1))
__global__ void rowdinv_kernel(const float* __restrict__ q, const float* __restrict__ tv,
                               const float* __restrict__ c, float* __restrict__ dinv) {
  const int row  = blockIdx.x * 4 + (threadIdx.x >> 6);   // [0, B*N)
  const int lane = threadIdx.x & 63;
  const int b    = row >> 11;
  const float4v* p  = (const float4v*)(q + (size_t)row * D_);
  const float4v* tp = (const float4v*)(tv + b * D_);
  float acc = 0.f;
  #pragma unroll
  for (int it = 0; it < 4; ++it) {
    float4v qv = p[it * 64 + lane];
    float4v tw = tp[it * 64 + lane];
    acc += qv.x * tw.x + qv.y * tw.y + qv.z * tw.z + qv.w * tw.w;
  }
  #pragma unroll
  for (int off = 32; off; off >>= 1) acc += __shfl_down(acc, off);
  if (lane == 0) dinv[row] = rsqrtf(fmaxf(acc + c[b], 1.0f));
}

extern "C" void kernel_launch(void* const* d_in, const int* in_sizes, int n_in,
                              void* d_out, int out_size, void* d_ws, size_t ws_size,
                              hipStream_t stream) {
  const float* q  = (const float*)d_in[0];
  // d_in[1] = k (unused), d_in[2] = v (unused)
  const float* W1 = (const float*)d_in[3];
  const float* b1 = (const float*)d_in[4];

  float* out  = (float*)d_out;                      // [B,N,N] normalized
  float* attn = out + (size_t)B_ * N_ * N_;         // [B,N,N] raw attn

  char* ws = (char*)d_ws;
  u16*   qbf  = (u16*)ws;                                   // 32 MiB
  u16*   qout = (u16*)(ws + (size_t)33554432);              // 32 MiB
  u16*   w1bf = (u16*)(ws + (size_t)67108864);              // 2 MiB
  float* qsum = (float*)(ws + (size_t)69206016);            // 32 KiB
  float* s    = (float*)(ws + (size_t)69238784);            // 32 KiB
  float* tv   = (float*)(ws + (size_t)69271552);            // 32 KiB
  float* c    = (float*)(ws + (size_t)69304320);            // 256 B
  float* dinv = (float*)(ws + (size_t)69304576);            // 64 KiB

  // zero the accumulated stats (qsum, s, tv, c) in one memset
  hipMemsetAsync(qsum, 0, 3 * B_ * D_ * sizeof(float) + 256, stream);

  // 1. convert q (+column sums) and W1 to bf16 (fused)
  cvt_fused<<<1024, 256, 0, stream>>>(q, qbf, qsum, W1, w1bf);

  // 2. GEMM1 (4-phase 256^2, mfma 32x32x16): qout = qbf @ w1bf^T + b1 (bf16)
  gemm8p<0><<<256, 512, 0, stream>>>(qbf, w1bf, b1, qout, nullptr);

  // 3. exact f32 rowsum stats: s -> (t, c) -> dinv
  s_kernel<<<dim3(B_ * D_ / 256, 16), 256, 0, stream>>>(qsum, W1, b1, s);
  tc_kernel<<<dim3(B_ * D_ / 256, 17), 256, 0, stream>>>(W1, s, b1, tv, c);
  rowdinv_kernel<<<(B_ * N_) / 4, 256, 0, stream>>>(q, tv, c, dinv);

  // 4. GEMM2 (4-phase 256^2, batched, mfma 32x32x16) + fused normalization
  gemm8p<1><<<512, 512, 0, stream>>>(qout, nullptr, dinv, attn, out);
}

// Round 11
// 216.370 us; speedup vs baseline: 1.1464x; 1.0506x over previous
//
#include <hip/hip_runtime.h>

#define B_ 8
#define N_ 2048
#define D_ 1024

using u16 = unsigned short;
typedef __attribute__((ext_vector_type(8))) short short8;
typedef __attribute__((ext_vector_type(4))) float f32x4;
typedef __attribute__((ext_vector_type(4))) float float4v;
typedef __attribute__((ext_vector_type(4))) int int4v;

static __device__ __forceinline__ float bf2f(u16 h) {
  return __uint_as_float(((unsigned)h) << 16);
}
static __device__ __forceinline__ u16 f2bf(float f) {
  unsigned u = __float_as_uint(f);
  u += 0x7FFFu + ((u >> 16) & 1u);   // round-to-nearest-even
  return (u16)(u >> 16);
}

static __device__ __forceinline__ void gload16(const void* g, void* l) {
  __builtin_amdgcn_global_load_lds((const __attribute__((address_space(1))) void*)g,
                                   (__attribute__((address_space(3))) void*)l, 16, 0, 0);
}

// =====================================================================
// 8-phase 256x256 bf16 GEMM (C = A * B^T), K = 1024.
// 512 threads = 8 waves (2M x 4N); per-wave output 128x64.
// LDS: 2 buffers x (A[256][64] + B[256][64]) bf16 = 128 KiB.
// Swizzle: logical (row, colbyte) stored at row*128 + (colbyte ^ ((row&7)<<4)).
// Write side: linear global_load_lds dest + pre-swizzled global source.
// BEST-MEASURED CONFIG (R3: 216.2 us, absmax 2.0).
// =====================================================================

__device__ __forceinline__ void stage(u16* __restrict__ L,
                                      const u16* __restrict__ gA,
                                      const u16* __restrict__ gB,
                                      int kof, int w) {
  #pragma unroll
  for (int i = 0; i < 4; ++i)
    gload16(gA + (size_t)(i * 64) * 1024 + kof, L + i * 4096 + w * 512);
  #pragma unroll
  for (int i = 0; i < 4; ++i)
    gload16(gB + (size_t)(i * 64) * 1024 + kof, L + 16384 + i * 4096 + w * 512);
}

__device__ __forceinline__ void ktile(const u16* __restrict__ Lb,
                                      int wr, int wc, int lane15, int ck0,
                                      f32x4 (&acc)[8][4]) {
  const u16* Ar = Lb + (wr * 128 + lane15) * 64;
  const u16* Br = Lb + 16384 + (wc * 64 + lane15) * 64;
  const int ck1 = ck0 ^ 32;
  short8 a[4], a2[4], b[4];

  // ---- phase 0: A m0-3 k0 + B n0-3 k0 (8 ds_read_b128) ----
  #pragma unroll
  for (int m = 0; m < 4; ++m) a[m] = *(const short8*)(Ar + m * 1024 + ck0);
  #pragma unroll
  for (int n = 0; n < 4; ++n) b[n] = *(const short8*)(Br + n * 1024 + ck0);
  __builtin_amdgcn_s_barrier();
  __builtin_amdgcn_s_setprio(1);
  #pragma unroll
  for (int m = 0; m < 4; ++m)
    #pragma unroll
    for (int n = 0; n < 4; ++n)
      acc[m][n] = __builtin_amdgcn_mfma_f32_16x16x32_bf16(a[m], b[n], acc[m][n], 0, 0, 0);
  __builtin_amdgcn_s_setprio(0);
  __builtin_amdgcn_s_barrier();

  // ---- phase 1: A m4-7 k0 (4 ds_read_b128) ----
  #pragma unroll
  for (int m = 0; m < 4; ++m) a2[m] = *(const short8*)(Ar + (m + 4) * 1024 + ck0);
  __builtin_amdgcn_s_barrier();
  __builtin_amdgcn_s_setprio(1);
  #pragma unroll
  for (int m = 0; m < 4; ++m)
    #pragma unroll
    for (int n = 0; n < 4; ++n)
      acc[m + 4][n] = __builtin_amdgcn_mfma_f32_16x16x32_bf16(a2[m], b[n], acc[m + 4][n], 0, 0, 0);
  __builtin_amdgcn_s_setprio(0);
  __builtin_amdgcn_s_barrier();

  // ---- phase 2: A m0-3 k1 + B n0-3 k1 ----
  #pragma unroll
  for (int m = 0; m < 4; ++m) a[m] = *(const short8*)(Ar + m * 1024 + ck1);
  #pragma unroll
  for (int n = 0; n < 4; ++n) b[n] = *(const short8*)(Br + n * 1024 + ck1);
  __builtin_amdgcn_s_barrier();
  __builtin_amdgcn_s_setprio(1);
  #pragma unroll
  for (int m = 0; m < 4; ++m)
    #pragma unroll
    for (int n = 0; n < 4; ++n)
      acc[m][n] = __builtin_amdgcn_mfma_f32_16x16x32_bf16(a[m], b[n], acc[m][n], 0, 0, 0);
  __builtin_amdgcn_s_setprio(0);
  __builtin_amdgcn_s_barrier();

  // ---- phase 3: A m4-7 k1 ----
  #pragma unroll
  for (int m = 0; m < 4; ++m) a2[m] = *(const short8*)(Ar + (m + 4) * 1024 + ck1);
  __builtin_amdgcn_s_barrier();
  __builtin_amdgcn_s_setprio(1);
  #pragma unroll
  for (int m = 0; m < 4; ++m)
    #pragma unroll
    for (int n = 0; n < 4; ++n)
      acc[m + 4][n] = __builtin_amdgcn_mfma_f32_16x16x32_bf16(a2[m], b[n], acc[m + 4][n], 0, 0, 0);
  __builtin_amdgcn_s_setprio(0);
  __builtin_amdgcn_s_barrier();
}

// MODE 0: C0 = bf16 out [M x 1024] with +bias     (GEMM1)
// MODE 1: batched symmetric, dual f32 out: attn=C0raw, out=C1 scaled by dinv (GEMM2)
template<int MODE>
__global__ __launch_bounds__(512, 2)
void gemm8p(const u16* __restrict__ Abase, const u16* __restrict__ Bbase,
            const float* __restrict__ aux,   // bias (MODE0) or dinv (MODE1)
            void* __restrict__ C0, float* __restrict__ C1)
{
  __shared__ u16 lds[2][32768];
  const int tid = threadIdx.x;
  const int w = tid >> 6, l = tid & 63;

  int tm0, tn0, z = 0;
  if (MODE == 0) {
    const int bid = blockIdx.x;                 // 256 blocks
    const int s = (bid & 7) * 32 + (bid >> 3);  // XCD-contiguous
    tm0 = (s >> 2) << 8;
    tn0 = (s & 3) << 8;
  } else {
    const int bid = blockIdx.x;                 // 512 blocks
    const int s = (bid & 7) * 64 + (bid >> 3);  // each XCD owns one batch
    z  = s >> 6;
    tm0 = ((s >> 3) & 7) << 8;
    tn0 = (s & 7) << 8;
  }
  const u16* A  = Abase + (MODE ? (size_t)z * N_ * D_ : 0);
  const u16* Bm = (MODE ? A : Bbase);

  // ---- staging source (pre-swizzled global col so linear LDS dest = swizzled layout)
  const int sr = w * 8 + (l >> 3);                       // row within 64-row round
  const int sc = (((l & 7) ^ (l >> 3)) << 4) >> 1;       // element col (swizzled)
  const u16* gA = A  + (size_t)(tm0 + sr) * 1024 + sc;
  const u16* gB = Bm + (size_t)(tn0 + sr) * 1024 + sc;

  // ---- fragment read addressing
  const int lane15 = l & 15, lhi = l >> 4;
  const int ck0 = ((lhi << 4) ^ ((l & 7) << 4)) >> 1;    // element col, kh=0
  const int wr = w >> 2, wc = w & 3;

  f32x4 acc[8][4];
  #pragma unroll
  for (int m = 0; m < 8; ++m)
    #pragma unroll
    for (int n = 0; n < 4; ++n)
      acc[m][n] = (f32x4){0.f, 0.f, 0.f, 0.f};

  // prologue: issue K-tiles 0,1
  stage(&lds[0][0], gA, gB, 0, w);
  stage(&lds[1][0], gA, gB, 64, w);

  for (int t = 0; t < 16; t += 2) {
    asm volatile("s_waitcnt vmcnt(8)" ::: "memory");   // tile t landed (all waves after barrier)
    __builtin_amdgcn_s_barrier();
    ktile(&lds[0][0], wr, wc, lane15, ck0, acc);
    stage(&lds[0][0], gA, gB, ((t + 2) & 15) * 64, w); // buf0 free (post-barrier)
    asm volatile("s_waitcnt vmcnt(8)" ::: "memory");   // tile t+1 landed
    __builtin_amdgcn_s_barrier();
    ktile(&lds[1][0], wr, wc, lane15, ck0, acc);
    stage(&lds[1][0], gA, gB, ((t + 3) & 15) * 64, w);
  }
  asm volatile("s_waitcnt vmcnt(0)" ::: "memory");     // drain DMA before endpgm

  // ---- epilogue: C/D layout col=lane&15, row=(lane>>4)*4+j ----
  const int rbase = tm0 + wr * 128 + lhi * 4;
  const int cbase = tn0 + wc * 64 + lane15;

  if (MODE == 0) {
    u16* C = (u16*)C0;
    #pragma unroll
    for (int m = 0; m < 8; ++m)
      #pragma unroll
      for (int n = 0; n < 4; ++n) {
        const int col = cbase + n * 16;
        const float bv = aux[col];
        #pragma unroll
        for (int j = 0; j < 4; ++j)
          C[(size_t)(rbase + m * 16 + j) * 1024 + col] = f2bf(acc[m][n][j] + bv);
      }
  } else {
    float* Cattn = (float*)C0 + (size_t)z * N_ * N_;
    float* Cout  = C1 + (size_t)z * N_ * N_;
    const float* dv = aux + z * N_;
    float di[8][4];
    #pragma unroll
    for (int m = 0; m < 8; ++m)
      #pragma unroll
      for (int j = 0; j < 4; ++j)
        di[m][j] = dv[rbase + m * 16 + j];
    #pragma unroll
    for (int m = 0; m < 8; ++m)
      #pragma unroll
      for (int n = 0; n < 4; ++n) {
        const int col = cbase + n * 16;
        const float dj = dv[col];
        #pragma unroll
        for (int j = 0; j < 4; ++j) {
          const size_t off = (size_t)(rbase + m * 16 + j) * N_ + col;
          const float a = acc[m][n][j];
          Cattn[off] = a;
          Cout[off]  = a * di[m][j] * dj;
        }
      }
  }
}

// ---------------- fused q f32->bf16 cvt + column sums -------------------------
// 256 blocks x 256 threads; thread owns (b, 32-row chunk, 8-col group).
__global__ void cvt_q_qsum(const float* __restrict__ q, u16* __restrict__ qbf,
                           float* __restrict__ qsum) {
  const int wi = blockIdx.x * 256 + threadIdx.x;
  const int d0 = (wi & 127) * 8;
  const int rc = (wi >> 7) & 63;
  const int b  = wi >> 13;
  const size_t base = ((size_t)b * N_ + rc * 32) * D_ + d0;
  float s[8];
  #pragma unroll
  for (int k = 0; k < 8; ++k) s[k] = 0.f;
  for (int r = 0; r < 32; ++r) {
    const float4v* p = (const float4v*)(q + base + (size_t)r * D_);
    float4v x = p[0], y = p[1];
    union { u16 h[8]; int4v v; } o;
    o.h[0] = f2bf(x.x); o.h[1] = f2bf(x.y); o.h[2] = f2bf(x.z); o.h[3] = f2bf(x.w);
    o.h[4] = f2bf(y.x); o.h[5] = f2bf(y.y); o.h[6] = f2bf(y.z); o.h[7] = f2bf(y.w);
    *(int4v*)(qbf + base + (size_t)r * D_) = o.v;
    s[0] += x.x; s[1] += x.y; s[2] += x.z; s[3] += x.w;
    s[4] += y.x; s[5] += y.y; s[6] += y.z; s[7] += y.w;
  }
  float* qs = qsum + b * D_ + d0;
  #pragma unroll
  for (int k = 0; k < 8; ++k) atomicAdd(qs + k, s[k]);
}

// ---------------- W1 f32 -> bf16 ---------------------------------------------
__global__ void cvt_f32_to_bf16(const float* __restrict__ in, u16* __restrict__ out, int n8) {
  const int stride = gridDim.x * blockDim.x;
  for (int i = blockIdx.x * blockDim.x + threadIdx.x; i < n8; i += stride) {
    const float4v* p = (const float4v*)in + (size_t)i * 2;
    float4v a = p[0], b = p[1];
    union { u16 h[8]; int4v v; } r;
    r.h[0] = f2bf(a.x); r.h[1] = f2bf(a.y); r.h[2] = f2bf(a.z); r.h[3] = f2bf(a.w);
    r.h[4] = f2bf(b.x); r.h[5] = f2bf(b.y); r.h[6] = f2bf(b.z); r.h[7] = f2bf(b.w);
    ((int4v*)out)[i] = r.v;
  }
}

// ---------------- exact f32 rowsum stats --------------------------------------
// s[b,e] = sum_d qsum[b,d] * W1[e,d] + N*b1[e]
__global__ void s_kernel(const float* __restrict__ qsum, const float* __restrict__ W1,
                         const float* __restrict__ b1, float* __restrict__ s) {
  const int idx = blockIdx.x * 256 + threadIdx.x;   // b*D + e
  const int b = idx >> 10, e = idx & (D_ - 1);
  const int d0 = blockIdx.y * 256;
  const float4v* wp = (const float4v*)(W1 + (size_t)e * D_ + d0);
  const float4v* qp = (const float4v*)(qsum + b * D_ + d0);
  float acc = 0.f;
  #pragma unroll 4
  for (int t = 0; t < 64; ++t) {
    float4v wv = wp[t], qv = qp[t];
    acc += wv.x * qv.x + wv.y * qv.y + wv.z * qv.z + wv.w * qv.w;
  }
  if (blockIdx.y == 0) acc += (float)N_ * b1[e];
  atomicAdd(&s[b * D_ + e], acc);
}

// t[b,d] = sum_e W1[e,d] * s[b,e]
__global__ void t_kernel(const float* __restrict__ W1, const float* __restrict__ s,
                         float* __restrict__ tv) {
  const int idx = blockIdx.x * 256 + threadIdx.x;   // b*D + d
  const int b = idx >> 10, d = idx & (D_ - 1);
  const int e0 = blockIdx.y * 256;
  const float* wp = W1 + (size_t)e0 * D_ + d;
  const float* sp = s + b * D_ + e0;
  float acc = 0.f;
  #pragma unroll 8
  for (int e = 0; e < 256; ++e) acc += wp[(size_t)e * D_] * sp[e];
  atomicAdd(&tv[b * D_ + d], acc);
}

// c[b] = sum_e b1[e] * s[b,e]
__global__ void c_kernel(const float* __restrict__ b1, const float* __restrict__ s,
                         float* __restrict__ c) {
  const int b = blockIdx.x;
  const int tid = threadIdx.x;
  float acc = 0.f;
  #pragma unroll
  for (int t = 0; t < 4; ++t) {
    const int e = tid + t * 256;
    acc += b1[e] * s[b * D_ + e];
  }
  __shared__ float red[4];
  #pragma unroll
  for (int off = 32; off; off >>= 1) acc += __shfl_down(acc, off);
  if ((tid & 63) == 0) red[tid >> 6] = acc;
  __syncthreads();
  if (tid == 0) c[b] = red[0] + red[1] + red[2] + red[3];
}

// dinv[b,i] = rsqrt(max(q[b,i,:] . t[b,:] + c[b], 1))
__global__ void rowdinv_kernel(const float* __restrict__ q, const float* __restrict__ tv,
                               const float* __restrict__ c, float* __restrict__ dinv) {
  const int row  = blockIdx.x * 4 + (threadIdx.x >> 6);   // [0, B*N)
  const int lane = threadIdx.x & 63;
  const int b    = row >> 11;
  const float4v* p  = (const float4v*)(q + (size_t)row * D_);
  const float4v* tp = (const float4v*)(tv + b * D_);
  float acc = 0.f;
  #pragma unroll
  for (int it = 0; it < 4; ++it) {
    float4v qv = p[it * 64 + lane];
    float4v tw = tp[it * 64 + lane];
    acc += qv.x * tw.x + qv.y * tw.y + qv.z * tw.z + qv.w * tw.w;
  }
  #pragma unroll
  for (int off = 32; off; off >>= 1) acc += __shfl_down(acc, off);
  if (lane == 0) dinv[row] = rsqrtf(fmaxf(acc + c[b], 1.0f));
}

extern "C" void kernel_launch(void* const* d_in, const int* in_sizes, int n_in,
                              void* d_out, int out_size, void* d_ws, size_t ws_size,
                              hipStream_t stream) {
  const float* q  = (const float*)d_in[0];
  // d_in[1] = k (unused), d_in[2] = v (unused)
  const float* W1 = (const float*)d_in[3];
  const float* b1 = (const float*)d_in[4];

  float* out  = (float*)d_out;                      // [B,N,N] normalized
  float* attn = out + (size_t)B_ * N_ * N_;         // [B,N,N] raw attn

  char* ws = (char*)d_ws;
  u16*   qbf  = (u16*)ws;                                   // 32 MiB
  u16*   qout = (u16*)(ws + (size_t)33554432);              // 32 MiB
  u16*   w1bf = (u16*)(ws + (size_t)67108864);              // 2 MiB
  float* qsum = (float*)(ws + (size_t)69206016);            // 32 KiB
  float* s    = (float*)(ws + (size_t)69238784);            // 32 KiB
  float* tv   = (float*)(ws + (size_t)69271552);            // 32 KiB
  float* c    = (float*)(ws + (size_t)69304320);            // 256 B
  float* dinv = (float*)(ws + (size_t)69304576);            // 64 KiB

  // zero the accumulated stats (qsum, s, t, c)
  hipMemsetAsync(qsum, 0, 3 * B_ * D_ * sizeof(float) + 256, stream);

  // 1. convert q (+column sums) and W1 to bf16
  cvt_q_qsum<<<256, 256, 0, stream>>>(q, qbf, qsum);
  cvt_f32_to_bf16<<<512, 256, 0, stream>>>(W1, w1bf, D_ * D_ / 8);

  // 2. GEMM1 (8-phase 256^2): qout = qbf @ w1bf^T + b1  (bf16 out)
  gemm8p<0><<<256, 512, 0, stream>>>(qbf, w1bf, b1, qout, nullptr);

  // 3. exact f32 rowsum: rowsum[b,i] = q[b,i,:].t[b,:] + c[b]
  s_kernel<<<dim3(B_ * D_ / 256, 4), 256, 0, stream>>>(qsum, W1, b1, s);
  t_kernel<<<dim3(B_ * D_ / 256, 4), 256, 0, stream>>>(W1, s, tv);
  c_kernel<<<B_, 256, 0, stream>>>(b1, s, c);
  rowdinv_kernel<<<(B_ * N_) / 4, 256, 0, stream>>>(q, tv, c, dinv);

  // 4. GEMM2 (8-phase 256^2, batched) + fused normalization epilogue
  gemm8p<1><<<512, 512, 0, stream>>>(qout, nullptr, dinv, attn, out);
}